// Round 1
// baseline (191.138 us; speedup 1.0000x reference)
//
#include <hip/hip_runtime.h>
#include <hip/hip_bf16.h>
#include <stdint.h>

// GAT layer: N=8192, F_IN=256, F_OUT=64, two branches (adj_in/adj_out), shared 'a'.
// out = elu(0.5*(softmax_masked(LR(h_in a_src + (h_in a_dst)^T), adj_in) @ h_in
//            + softmax_masked(...out...) @ h_out))

#define NN 8192
#define ALPHA 0.2f
#define L2E 1.44269504088896f

typedef _Float16 f16;
typedef _Float16 f16x4 __attribute__((ext_vector_type(4)));
typedef _Float16 f16x8 __attribute__((ext_vector_type(8)));
typedef float f32x4 __attribute__((ext_vector_type(4)));

// workspace layout (bytes)
#define WS_WT    0u         // f16 [128][256]  (transposed W_in|W_out)
#define WS_HT    65536u     // f16 [2][64][8192] (h transposed, per branch)
#define WS_SRC   2162688u   // f32 [2][8192]
#define WS_DST   2228224u   // f32 [2][8192]
#define WS_DMAX  2293760u   // f32 [2]
#define WS_PACC  2294016u   // f32 [2][8192][64]

// ---------------- kernel 1: WT[c][k] = W[k][c] as f16 ----------------
__global__ __launch_bounds__(256) void k1_wt(const float* __restrict__ Win,
                                             const float* __restrict__ Wout,
                                             f16* __restrict__ WT) {
    int c = blockIdx.x;          // 0..127 combined col
    int k = threadIdx.x;         // 0..255
    const float* W = (c < 64) ? Win : Wout;
    int cc = c & 63;
    WT[(size_t)c * 256 + k] = (f16)W[(size_t)k * 64 + cc];
}

// ---------------- kernel 2: h = x@W (MFMA), emit HT f16 + src/dst ----------------
__global__ __launch_bounds__(64) void k2_h(const float* __restrict__ x,
                                           const f16* __restrict__ WT,
                                           const float* __restrict__ a,
                                           f16* __restrict__ HT,
                                           float* __restrict__ srcw,
                                           float* __restrict__ dstw) {
    int l = threadIdx.x;
    int l15 = l & 15, lhi = l >> 4;
    int row0 = blockIdx.x * 16;

    f32x4 acc[8];
#pragma unroll
    for (int n = 0; n < 8; n++) { acc[n][0]=0.f; acc[n][1]=0.f; acc[n][2]=0.f; acc[n][3]=0.f; }

#pragma unroll
    for (int kc = 0; kc < 8; kc++) {
        int k = kc * 32 + lhi * 8;
        const float* xp = x + (size_t)(row0 + l15) * 256 + k;
        float4 xa = *(const float4*)xp;
        float4 xb = *(const float4*)(xp + 4);
        f16x8 af;
        af[0]=(f16)xa.x; af[1]=(f16)xa.y; af[2]=(f16)xa.z; af[3]=(f16)xa.w;
        af[4]=(f16)xb.x; af[5]=(f16)xb.y; af[6]=(f16)xb.z; af[7]=(f16)xb.w;
#pragma unroll
        for (int n = 0; n < 8; n++) {
            f16x8 bf = *(const f16x8*)(WT + (size_t)(16 * n + l15) * 256 + k);
            acc[n] = __builtin_amdgcn_mfma_f32_16x16x32_f16(af, bf, acc[n], 0, 0, 0);
        }
    }

    float as4[4], ad4[4];
#pragma unroll
    for (int nn = 0; nn < 4; nn++) {
        as4[nn] = a[16 * nn + l15];
        ad4[nn] = a[64 + 16 * nn + l15];
    }

    float s_in[4] = {0,0,0,0}, d_in[4] = {0,0,0,0};
    float s_out[4] = {0,0,0,0}, d_out[4] = {0,0,0,0};

#pragma unroll
    for (int n = 0; n < 8; n++) {
        int b = n >> 2;
        int ci = 16 * (n & 3) + l15;
        f16x4 hv;
#pragma unroll
        for (int q = 0; q < 4; q++) hv[q] = (f16)acc[n][q];
        *(f16x4*)(HT + (size_t)b * 524288 + (size_t)ci * 8192 + row0 + 4 * lhi) = hv;
#pragma unroll
        for (int q = 0; q < 4; q++) {
            float v = acc[n][q];
            if (b == 0) { s_in[q]  += v * as4[n & 3]; d_in[q]  += v * ad4[n & 3]; }
            else        { s_out[q] += v * as4[n & 3]; d_out[q] += v * ad4[n & 3]; }
        }
    }

#pragma unroll
    for (int q = 0; q < 4; q++) {
#pragma unroll
        for (int m = 1; m < 16; m <<= 1) {
            s_in[q]  += __shfl_xor(s_in[q],  m, 64);
            d_in[q]  += __shfl_xor(d_in[q],  m, 64);
            s_out[q] += __shfl_xor(s_out[q], m, 64);
            d_out[q] += __shfl_xor(d_out[q], m, 64);
        }
    }
    if (l15 == 0) {
        int row = row0 + 4 * lhi;
#pragma unroll
        for (int q = 0; q < 4; q++) {
            srcw[row + q]        = s_in[q];
            srcw[8192 + row + q] = s_out[q];
            dstw[row + q]        = d_in[q];
            dstw[8192 + row + q] = d_out[q];
        }
    }
}

// ---------------- kernel 3: per-branch max of dst ----------------
__global__ __launch_bounds__(256) void k3_dmax(const float* __restrict__ dstw,
                                               float* __restrict__ dmax) {
    __shared__ float red[2][4];
    int t = threadIdx.x;
    int l = t & 63, w = t >> 6;
    for (int b = 0; b < 2; b++) {
        float v = -1e30f;
        for (int i = t; i < 8192; i += 256) v = fmaxf(v, dstw[b * 8192 + i]);
#pragma unroll
        for (int m = 1; m < 64; m <<= 1) v = fmaxf(v, __shfl_xor(v, m, 64));
        if (l == 0) red[b][w] = v;
    }
    __syncthreads();
    if (t == 0) dmax[0] = fmaxf(fmaxf(red[0][0], red[0][1]), fmaxf(red[0][2], red[0][3]));
    if (t == 1) dmax[1] = fmaxf(fmaxf(red[1][0], red[1][1]), fmaxf(red[1][2], red[1][3]));
}

// ---------------- kernel 4: fused masked-softmax-attention (one branch, 16 rows/block) ----------------
__global__ __launch_bounds__(256) void k4_main(const int* __restrict__ adj_in,
                                               const int* __restrict__ adj_out,
                                               const f16* __restrict__ HT,
                                               const float* __restrict__ srcw,
                                               const float* __restrict__ dstw,
                                               const float* __restrict__ dmaxp,
                                               float* __restrict__ pacc) {
    __shared__ f16 Wlds[16 * 72];    // weight tile [16 rows][64 j] padded to 72
    __shared__ f16 HTlds[64 * 72];   // H^T tile [64 cols][64 j] padded to 72
    __shared__ float dsL[2][64];     // dst*log2e, double buffered
    __shared__ float dnl[16][17];
    __shared__ float dnr[16];

    int t = threadIdx.x;
    int branch = blockIdx.x & 1;
    int row0 = (blockIdx.x >> 1) * 16;
    const int* adj = branch ? adj_out : adj_in;
    const f16* htg = HT + (size_t)branch * 524288;
    const float* srcb = srcw + branch * 8192;
    const float* dstb = dstw + branch * 8192;
    float dmaxv = dmaxp[branch];

    int r = t & 15, g = t >> 4;      // weight role: row r, j-quad g
    float srcv = srcb[row0 + r];
    float md = srcv + dmaxv;
    float mlog = fmaxf(md, ALPHA * md) * L2E;   // LR(src+dmax)*log2e  (upper bound shift)
    float srcL = srcv * L2E;

    int l = t & 63, wv = t >> 6;     // MFMA role: wave wv owns n-tile wv
    int l15 = l & 15, lhi = l >> 4;

    f32x4 acc; acc[0]=0.f; acc[1]=0.f; acc[2]=0.f; acc[3]=0.f;
    float dn = 0.f;

    // prologue
    if (t < 64) dsL[0][t] = dstb[t] * L2E;
    const int* adjrow = adj + (size_t)(row0 + r) * 8192 + 4 * g;
    int4 adjcur = *(const int4*)(adjrow);
    __syncthreads();

    for (int s = 0; s < 128; s++) {
        int j0 = s * 64;
        int snext = (s < 127) ? s + 1 : s;
        int4 adjnext = *(const int4*)(adjrow + (size_t)snext * 64);

        // stage H^T tile into regs (each thread 2 chunks of 8 f16)
        f16x8 h0 = *(const f16x8*)(htg + (size_t)(t >> 3) * 8192 + j0 + (t & 7) * 8);
        f16x8 h1 = *(const f16x8*)(htg + (size_t)((t + 256) >> 3) * 8192 + j0 + (t & 7) * 8);

        if (t < 64) dsL[(s + 1) & 1][t] = dstb[(size_t)snext * 64 + t] * L2E;

        // weights: w = adj ? exp2(LR(src+dst)*log2e - mlog) : 0
        {
            float4 dv = *(const float4*)&dsL[s & 1][4 * g];
            const float* dvp = (const float*)&dv;
            const int* ap = (const int*)&adjcur;
            f16x4 wq;
#pragma unroll
            for (int jj = 0; jj < 4; jj++) {
                float xp = srcL + dvp[jj];
                float lr = fmaxf(xp, ALPHA * xp);
                float e = exp2f(lr - mlog);
                e = (ap[jj] > 0) ? e : 0.f;
                dn += e;
                wq[jj] = (f16)e;
            }
            *(f16x4*)(Wlds + r * 72 + 4 * g) = wq;
        }

        // write staged H^T tile
        *(f16x8*)(HTlds + (size_t)(t >> 3) * 72 + (t & 7) * 8) = h0;
        *(f16x8*)(HTlds + (size_t)((t + 256) >> 3) * 72 + (t & 7) * 8) = h1;
        __syncthreads();

        // MFMA: acc += Wtile(16x64) @ Htile(64x16-per-wave)
#pragma unroll
        for (int kc = 0; kc < 2; kc++) {
            f16x8 af = *(const f16x8*)(Wlds + l15 * 72 + kc * 32 + lhi * 8);
            f16x8 bf = *(const f16x8*)(HTlds + (16 * wv + l15) * 72 + kc * 32 + lhi * 8);
            acc = __builtin_amdgcn_mfma_f32_16x16x32_f16(af, bf, acc, 0, 0, 0);
        }
        __syncthreads();
        adjcur = adjnext;
    }

    // denominator reduce (16 partials per row)
    dnl[r][g] = dn;
    __syncthreads();
    if (t < 16) {
        float sum = 0.f;
#pragma unroll
        for (int gg = 0; gg < 16; gg++) sum += dnl[t][gg];
        dnr[t] = 1.0f / sum;
    }
    __syncthreads();

    float* pb = pacc + (size_t)branch * 524288 + (size_t)row0 * 64;
#pragma unroll
    for (int q = 0; q < 4; q++) {
        int rr = 4 * lhi + q;
        pb[(size_t)rr * 64 + 16 * wv + l15] = acc[q] * dnr[rr];
    }
}

// ---------------- kernel 5: combine branches + ELU ----------------
__global__ __launch_bounds__(256) void k5_combine(const float* __restrict__ pacc,
                                                  float* __restrict__ out) {
    size_t idx = (size_t)blockIdx.x * 256 + threadIdx.x;   // float4 index
    float4 p0 = *(const float4*)(pacc + idx * 4);
    float4 p1 = *(const float4*)(pacc + 524288 + idx * 4);
    float4 o;
    float v;
    v = 0.5f * (p0.x + p1.x); o.x = (v > 0.f) ? v : (exp2f(v * L2E) - 1.f);
    v = 0.5f * (p0.y + p1.y); o.y = (v > 0.f) ? v : (exp2f(v * L2E) - 1.f);
    v = 0.5f * (p0.z + p1.z); o.z = (v > 0.f) ? v : (exp2f(v * L2E) - 1.f);
    v = 0.5f * (p0.w + p1.w); o.w = (v > 0.f) ? v : (exp2f(v * L2E) - 1.f);
    *(float4*)(out + idx * 4) = o;
}

extern "C" void kernel_launch(void* const* d_in, const int* in_sizes, int n_in,
                              void* d_out, int out_size, void* d_ws, size_t ws_size,
                              hipStream_t stream) {
    const float* x       = (const float*)d_in[0];
    const int*   adj_in  = (const int*)d_in[1];
    const int*   adj_out = (const int*)d_in[2];
    const float* W_in    = (const float*)d_in[3];
    const float* W_out   = (const float*)d_in[4];
    const float* a       = (const float*)d_in[5];
    float* out = (float*)d_out;

    char* ws = (char*)d_ws;
    f16*   WT   = (f16*)(ws + WS_WT);
    f16*   HT   = (f16*)(ws + WS_HT);
    float* srcw = (float*)(ws + WS_SRC);
    float* dstw = (float*)(ws + WS_DST);
    float* dmax = (float*)(ws + WS_DMAX);
    float* pacc = (float*)(ws + WS_PACC);
    // requires ws_size >= ~6.2 MB

    hipLaunchKernelGGL(k1_wt,     dim3(128),  dim3(256), 0, stream, W_in, W_out, WT);
    hipLaunchKernelGGL(k2_h,      dim3(512),  dim3(64),  0, stream, x, WT, a, HT, srcw, dstw);
    hipLaunchKernelGGL(k3_dmax,   dim3(1),    dim3(256), 0, stream, dstw, dmax);
    hipLaunchKernelGGL(k4_main,   dim3(1024), dim3(256), 0, stream, adj_in, adj_out, HT, srcw, dstw, dmax, pacc);
    hipLaunchKernelGGL(k5_combine,dim3(512),  dim3(256), 0, stream, pacc, out);
}